// Round 15
// baseline (231.853 us; speedup 1.0000x reference)
//
#include <hip/hip_runtime.h>
#include <math.h>

typedef unsigned short us;
typedef __attribute__((ext_vector_type(8))) short frag8;
typedef __attribute__((ext_vector_type(8))) unsigned short u8v;
typedef __attribute__((ext_vector_type(4))) float f4;
typedef __attribute__((ext_vector_type(2))) float f2;
typedef unsigned long long u64;

#define B_   2
#define T_   1024
#define DM_  1024
#define D_   2048
#define N_   16
#define DTR_ 128
#define NDBC 160           // DTR + 2N
#define ROWS (B_*T_)       // 2048
#define EPS_ 1e-6f
#define NCH  32            // scan chunks per channel
#define CLEN (T_/NCH)      // 32 steps per chunk
#define KSPL 8             // split-K factor for dbc GEMM
#define OSPL 4             // split-K factor for out-proj GEMM
#define L2E  1.44269504f   // log2(e)

__device__ __forceinline__ float us2f(us s){
    return __uint_as_float(((unsigned int)s) << 16);
}
__device__ __forceinline__ us f2us(float f){   // RTN-even fp32->bf16
    unsigned int u = __float_as_uint(f);
    return (us)((u + 0x7FFF + ((u >> 16) & 1)) >> 16);
}
// raw v_exp_f32: D = 2^S0 (1 instr; __expf emits v_mul(log2e)+v_exp)
__device__ __forceinline__ float exp2i(float x){
    float r; asm("v_exp_f32 %0, %1" : "=v"(r) : "v"(x)); return r;
}
__device__ __forceinline__ float rcpi(float x){
    return __builtin_amdgcn_rcpf(x);
}

// async global->LDS, 16B per lane. LDS dest is wave-uniform base + lane*16.
__device__ __forceinline__ void async16(const void* g, void* l){
    __builtin_amdgcn_global_load_lds(
        (const __attribute__((address_space(1))) void*)g,
        (__attribute__((address_space(3)))       void*)l, 16, 0, 0);
}

// one DPP accumulate step (dpp_ctrl must be a literal constant)
template<int CTRL>
__device__ __forceinline__ float dpp_add(float x){
    int t = __builtin_amdgcn_update_dpp(0, __float_as_int(x), CTRL, 0xF, 0xF, true);
    return x + __int_as_float(t);
}
// 4-lane (quad) sum via two quad_perm DPP adds; all 4 lanes get the total
__device__ __forceinline__ float sum4_quad(float x){
    x = dpp_add<0xB1>(x);   // quad_perm [1,0,3,2]
    x = dpp_add<0x4E>(x);   // quad_perm [2,3,0,1]
    return x;
}

// ---- combined preprocessing: 4 weight transposes + RMSNorm (merged) ----
__global__ __launch_bounds__(256) void prep_weights(
    const float* __restrict__ in_W,  const float* __restrict__ out_W,
    const float* __restrict__ dbc_W, const float* __restrict__ dup_W,
    us* __restrict__ inWt, us* __restrict__ outWt,
    us* __restrict__ dbcWt, us* __restrict__ dupWt,
    const float* __restrict__ x, const float* __restrict__ rms_w,
    us* __restrict__ hbf)
{
    int bid = blockIdx.x;
    int tx = threadIdx.x, ty = threadIdx.y;   // 32 x 8
    if (bid >= 6720) {   // ---- RMSNorm path ----
        const int row = bid - 6720;
        const int tid = ty * 32 + tx;
        const float* xr = x + (size_t)row * DM_;
        float vals[4], ss = 0.f;
#pragma unroll
        for (int i = 0; i < 4; ++i) { vals[i] = xr[tid + i*256]; ss += vals[i]*vals[i]; }
#pragma unroll
        for (int off = 32; off >= 1; off >>= 1) ss += __shfl_xor(ss, off, 64);
        __shared__ float red[4];
        if ((tid & 63) == 0) red[tid >> 6] = ss;
        __syncthreads();
        float scale = rsqrtf((red[0]+red[1]+red[2]+red[3]) / (float)DM_ + EPS_);
#pragma unroll
        for (int i = 0; i < 4; ++i)
            hbf[(size_t)row * DM_ + tid + i*256] = f2us(vals[i] * scale * rms_w[tid + i*256]);
        return;
    }
    __shared__ us tile[32][33];
    const float* src; us* dst; int C, R, TX, rel;
    if (bid < 4096)      { src = in_W;  dst = inWt;  R = 1024; C = 4096; TX = 128; rel = bid; }
    else if (bid < 6144) { src = out_W; dst = outWt; R = 2048; C = 1024; TX = 32;  rel = bid - 4096; }
    else if (bid < 6464) { src = dbc_W; dst = dbcWt; R = 2048; C = 160;  TX = 5;   rel = bid - 6144; }
    else                 { src = dup_W; dst = dupWt; R = 128;  C = 2048; TX = 64;  rel = bid - 6464; }
    int c0 = (rel % TX) * 32, r0 = (rel / TX) * 32;
    for (int i = ty; i < 32; i += 8)
        tile[i][tx] = f2us(src[(size_t)(r0 + i) * C + c0 + tx]);
    __syncthreads();
    for (int i = ty; i < 32; i += 8)
        dst[(size_t)(c0 + i) * R + r0 + tx] = tile[tx][i];
}

// ---------- MFMA GEMM: C[M,N] = A[M,K](bf16) * Bt[N,K](bf16)^T + bias --------
// Block tile 128 x BN (BN in {128,64,32}) / 4 waves / mfma_f32_16x16x32_bf16.
template<int EPI, bool RB, int BN>
__global__ __launch_bounds__(256) void mgemm(
    const us*    __restrict__ A,     // [M][ld]
    const us*    __restrict__ Bt,    // [N][ld]
    const float* __restrict__ bias,
    float*       __restrict__ Cf,
    us*          __restrict__ Caux,
    const float* __restrict__ resid, // EPI==2
    float*       __restrict__ bct,   // EPI==3
    int M, int N, int K, int ld)
{
    __shared__ us As[128*64];
    __shared__ us Bs[BN*64];
    const int tid = threadIdx.x;
    const int bm = blockIdx.y * 128;
    const int bn = blockIdx.x * BN;
    const int w = tid >> 6, lane = tid & 63;
    constexpr int WROWS = (BN == 128) ? 64 : 32;   // wave rows
    constexpr int NI = WROWS / 16;                 // 4 or 2
    constexpr int NJ = (BN == 32) ? 2 : 4;         // wave cols / 16
    const int wr = (BN == 128) ? (w >> 1) : w;
    const int wc = (BN == 128) ? (w & 1) : 0;
    const int m16 = lane & 15, quad = lane >> 4;

    const us* Ak = A;
    const us* Bk = Bt;
    if constexpr (EPI == 5) {
        const size_t koff = (size_t)blockIdx.z * K;
        Ak += koff; Bk += koff;
        Cf += (size_t)blockIdx.z * (size_t)M * N;
    }

    f4 acc[NI][NJ];
#pragma unroll
    for (int i = 0; i < NI; ++i)
#pragma unroll
        for (int j = 0; j < NJ; ++j)
            acc[i][j] = (f4){0.f, 0.f, 0.f, 0.f};

    for (int k0 = 0; k0 < K; k0 += 64) {
        __syncthreads();   // prior iter's frag reads done before overwrite
#pragma unroll
        for (int q = 0; q < 4; ++q) {          // A: 1024 chunks, 4/thread
            int cb = (w*4 + q)*64 + lane;
            int row = cb >> 3, c8 = (cb & 7)*8;
            async16(Ak + (size_t)(bm + row) * ld + k0 + c8, &As[cb*8]);
        }
#pragma unroll
        for (int q = 0; q < BN/32; ++q) {      // B: BN*8 chunks
            int cb = (w*(BN/32) + q)*64 + lane;
            int row = cb >> 3, c8 = (cb & 7)*8;
            async16(Bk + (size_t)(bn + row) * ld + k0 + c8, &Bs[cb*8]);
        }
        __syncthreads();   // vmcnt(0) drained here -> LDS valid
#pragma unroll
        for (int ks = 0; ks < 64; ks += 32) {
            frag8 af[NI], bfr[NJ];
#pragma unroll
            for (int i = 0; i < NI; ++i)
                af[i] = *(const frag8*)&As[(wr*WROWS + i*16 + m16)*64 + ks + quad*8];
#pragma unroll
            for (int j = 0; j < NJ; ++j)
                bfr[j] = *(const frag8*)&Bs[(wc*64 + j*16 + m16)*64 + ks + quad*8];
#pragma unroll
            for (int i = 0; i < NI; ++i)
#pragma unroll
                for (int j = 0; j < NJ; ++j)
                    acc[i][j] = __builtin_amdgcn_mfma_f32_16x16x32_bf16(af[i], bfr[j], acc[i][j], 0, 0, 0);
        }
    }

#pragma unroll
    for (int i = 0; i < NI; ++i) {
#pragma unroll
        for (int j = 0; j < NJ; ++j) {
            int col = bn + wc*64 + j*16 + m16;
            if (col >= N) continue;
            float bvc = (RB || EPI == 5) ? 0.f : bias[col];
#pragma unroll
            for (int r = 0; r < 4; ++r) {
                int row = bm + wr*WROWS + i*16 + quad*4 + r;
                float v = acc[i][j][r] + (EPI == 5 ? 0.f : (RB ? bias[row] : bvc));
                if constexpr (EPI == 1) {
                    // softplus -> bf16 (delta_t)
                    v = fmaxf(v, 0.f) + __logf(1.f + __expf(-fabsf(v)));
                    Caux[(size_t)row * N + col] = f2us(v);
                } else if constexpr (EPI == 2) {
                    v += resid[(size_t)row * N + col];
                    Cf[(size_t)row * N + col] = v;
                } else if constexpr (EPI == 3) {
                    if (col < DTR_) Caux[(size_t)row * DTR_ + col] = f2us(v);
                    else            bct [(size_t)row * 32 + (col - DTR_)] = v;
                } else if constexpr (EPI == 4) {
                    // all columns bf16 into projb [rows][N] (x1 | g)
                    Caux[(size_t)row * N + col] = f2us(v);
                } else {   // EPI 0 and EPI 5 (partial)
                    Cf[(size_t)row * N + col] = v;
                }
            }
        }
    }
}

// ---- split-K reduce for dbc: sum 8 partials + bias -> dtrb bf16 + bct fp32 ----
__global__ __launch_bounds__(256) void dbc_reduce(
    const float* __restrict__ part,   // [KSPL][ROWS][NDBC]
    const float* __restrict__ bias,
    us*    __restrict__ dtrb,         // [ROWS][DTR]
    float* __restrict__ bct)          // [ROWS][32]
{
    int idx = blockIdx.x * 256 + threadIdx.x;   // < ROWS*NDBC
    int row = idx / NDBC, col = idx - row * NDBC;
    float v = bias[col];
#pragma unroll
    for (int z = 0; z < KSPL; ++z)
        v += part[(size_t)z * ROWS * NDBC + idx];
    if (col < DTR_) dtrb[(size_t)row * DTR_ + col] = f2us(v);
    else            bct [(size_t)row * 32 + (col - DTR_)] = v;
}

// ---- split-K reduce for out-proj: sum 4 partials + bias + residual ----
__global__ __launch_bounds__(256) void out_reduce(
    const float* __restrict__ part,   // [OSPL][ROWS][DM_]
    const float* __restrict__ bias,   // [DM_]
    const float* __restrict__ resid,  // [ROWS][DM_]
    float* __restrict__ out)
{
    int idx = (blockIdx.x * 256 + threadIdx.x) * 4;  // element index, f4 chunks
    int col = idx & (DM_ - 1);
    f4 v = *(const f4*)&bias[col];
    v += *(const f4*)&resid[idx];
#pragma unroll
    for (int z = 0; z < OSPL; ++z)
        v += *(const f4*)&part[(size_t)z * ROWS * DM_ + idx];
    *(f4*)&out[idx] = v;
}

// --- depthwise causal conv (K=4) + SiLU, 8 channels/thread (u8v taps) -------
__global__ __launch_bounds__(256) void conv_silu_kernel(
    const us*    __restrict__ projb,  // [rows][2D]: cols<D = x1pre, >=D = g
    const float* __restrict__ cw,
    const float* __restrict__ cb,
    us*          __restrict__ x1cb,
    us*          __restrict__ x1tb,
    us*          __restrict__ g_t)
{
    __shared__ us tileX[64][33];
    __shared__ us tileG[64][33];
    const int tid = threadIdx.x;
    const int dg = tid & 7, r = tid >> 3;   // 8 d-groups x 32 rows
    const int d0 = blockIdx.x * 64, r0 = blockIdx.y * 32;
    const int d8 = d0 + dg * 8;
    const int row = r0 + r;
    const int t = row & (T_ - 1);
    const us* base = projb + (size_t)row * (2*D_) + d8;
    const u8v zv = {0,0,0,0,0,0,0,0};
    u8v tap3 = *(const u8v*)base;
    u8v tap2 = (t >= 1) ? *(const u8v*)(base - 2*D_) : zv;
    u8v tap1 = (t >= 2) ? *(const u8v*)(base - 4*D_) : zv;
    u8v tap0 = (t >= 3) ? *(const u8v*)(base - 6*D_) : zv;
    u8v gv   = *(const u8v*)(base + D_);
    u8v outv;
#pragma unroll
    for (int e = 0; e < 8; ++e) {
        int d = d8 + e;
        f4 w = *(const f4*)&cw[d*4];
        float acc = cb[d];
        acc = fmaf(w[3], us2f(tap3[e]), acc);
        acc = fmaf(w[2], us2f(tap2[e]), acc);
        acc = fmaf(w[1], us2f(tap1[e]), acc);
        acc = fmaf(w[0], us2f(tap0[e]), acc);
        float sg = rcpi(1.f + exp2i(-acc * L2E));
        us uv = f2us(acc * sg);
        outv[e] = uv;
        tileX[dg*8 + e][r] = uv;
        tileG[dg*8 + e][r] = gv[e];
    }
    *(u8v*)&x1cb[(size_t)row * D_ + d8] = outv;
    __syncthreads();
#pragma unroll
    for (int it = 0; it < 8; ++it) {
        int dd = it*8 + (tid >> 5);     // 0..63
        int rr = tid & 31;
        x1tb[(size_t)(d0 + dd) * ROWS + r0 + rr] = tileX[dd][rr];
        g_t [(size_t)(d0 + dd) * ROWS + r0 + rr] = tileG[dd][rr];
    }
}

// ------- chunked selective scan + gate, FOUR channels per block --------------
// v15: B/C depend only on (b,t,n); v6's 2-channel pairing (+26%) extends to 4
// channels: one Bv/Cv f4 load feeds 4 independent chains (2x ILP for the
// latency half, ~20% fewer VALU/channel). All per-channel state in NAMED vars
// via macros (no runtime-indexed reg arrays -- the v2 lesson). Output packs 4
// adjacent-d bf16 -> one 8B store; XCD-local swizzle over 1024 blocks keeps
// each 64B ybf line on one XCD (v10 invariant: line = 8 consecutive swz).
#define SCAN_CH(M) M(0) M(1) M(2) M(3)

__global__ __launch_bounds__(128, 2) void scan_block_kernel(
    const us*    __restrict__ delta_t,  // [d][rows] bf16
    const us*    __restrict__ x1tb,
    const float* __restrict__ bct,    // [rows][32]: [0:16]=B_n, [16:32]=C_n
    const float* __restrict__ A_log,
    const us*    __restrict__ g_t,
    us*          __restrict__ ybf)    // [rows][D] row-major
{
    __shared__ float ys[4][T_ + NCH];   // swizzle f(t) = t + (t>>5)
    __shared__ f4 PSl[4][NCH][9];       // [ch][c][2ng+(0,1)]; +1 pad col

    const int tid = threadIdx.x;       // 128
    // XCD-local channel mapping over 1024 blocks: XCD x owns swz [x*128,(x+1)*128)
    const int lin = blockIdx.x;        // 0..1023
    const int swz = (lin & 7) * ((B_*D_/4) >> 3) + (lin >> 3);
    const int pr = swz & (D_/4 - 1);
    const int b  = swz >> 9;
    const int d0 = pr * 4;
    const int ng = tid & 3;            // states 4ng .. 4ng+3
    const int c  = tid >> 2;           // chunk 0..31
    const size_t rb  = (size_t)b * T_;
    const size_t cb0 = (size_t)d0 * ROWS + rb;   // ch k at +k*ROWS
    const int t0 = c * CLEN;

    // per-state coefficients ac2_n = -exp(A_log[d][n]) * log2(e)
#define COEF(k) \
    f4 al_##k = *(const f4*)&A_log[(d0 + k) * N_ + ng * 4]; \
    const f2 a01_##k = (f2){-__expf(al_##k[0])*L2E, -__expf(al_##k[1])*L2E}; \
    const f2 a23_##k = (f2){-__expf(al_##k[2])*L2E, -__expf(al_##k[3])*L2E};
    SCAN_CH(COEF)
#undef COEF

#define PTRS(k) \
    const us* __restrict__ dp_##k = delta_t + cb0 + (size_t)(k)*ROWS + t0; \
    const us* __restrict__ xp_##k = x1tb   + cb0 + (size_t)(k)*ROWS + t0;
    SCAN_CH(PTRS)
#undef PTRS
    const float* __restrict__ bp = bct + (size_t)(rb + t0) * 32 + ng * 4;
    const float* __restrict__ cp = bp + 16;

    // ---------------- pass 1: per-chunk (Dsum, S), 4 channels ---------------
#define ST1(k) float Ds_##k = 0.f; f2 S01_##k={0.f,0.f}, S23_##k={0.f,0.f};
    SCAN_CH(ST1)
#undef ST1
#pragma unroll
    for (int g = 0; g < 4; ++g) {
#define LOADS(k) u8v dV_##k = *(const u8v*)&dp_##k[g*8]; \
                 u8v xV_##k = *(const u8v*)&xp_##k[g*8];
        SCAN_CH(LOADS)
#undef LOADS
#pragma unroll
        for (int j = 0; j < 8; ++j) {
            f4 Bv = *(const f4*)&bp[(size_t)(g*8 + j) * 32];
#define STEP1(k) { \
            float dj = us2f(dV_##k[j]); \
            float dx = dj * us2f(xV_##k[j]); \
            Ds_##k += dj; \
            f2 jv = (f2){dj, dj}; \
            f2 e01 = jv*a01_##k, e23 = jv*a23_##k; \
            f2 x01 = (f2){exp2i(e01.x), exp2i(e01.y)}; \
            f2 x23 = (f2){exp2i(e23.x), exp2i(e23.y)}; \
            S01_##k = x01*S01_##k + (f2){dx*Bv[0], dx*Bv[1]}; \
            S23_##k = x23*S23_##k + (f2){dx*Bv[2], dx*Bv[3]}; }
            SCAN_CH(STEP1)
#undef STEP1
        }
    }
    // P_n = exp2(ac2_n * Dsum)
#define STORE_PS(k) { \
        f2 P01 = (f2){exp2i(a01_##k.x*Ds_##k), exp2i(a01_##k.y*Ds_##k)}; \
        f2 P23 = (f2){exp2i(a23_##k.x*Ds_##k), exp2i(a23_##k.y*Ds_##k)}; \
        PSl[k][c][2*ng+0] = (f4){P01.x, P01.y, S01_##k.x, S01_##k.y}; \
        PSl[k][c][2*ng+1] = (f4){P23.x, P23.y, S23_##k.x, S23_##k.y}; }
    SCAN_CH(STORE_PS)
#undef STORE_PS
    __syncthreads();

    // ---------------- inter-chunk prefix (serial over c2 < c) ----------------
#define HDEF(k) f2 h01_##k={0.f,0.f}, h23_##k={0.f,0.f};
    SCAN_CH(HDEF)
#undef HDEF
    for (int c2 = 0; c2 < c; ++c2) {
#define PFX(k) { \
        f4 p0 = PSl[k][c2][2*ng+0], p1 = PSl[k][c2][2*ng+1]; \
        h01_##k = (f2){p0[0],p0[1]}*h01_##k + (f2){p0[2],p0[3]}; \
        h23_##k = (f2){p1[0],p1[1]}*h23_##k + (f2){p1[2],p1[3]}; }
        SCAN_CH(PFX)
#undef PFX
    }

    // ---------------- pass 2: recompute a/d, emit y (4 channels) ------------
#pragma unroll
    for (int g = 0; g < 4; ++g) {
#define LOADS(k) u8v dV_##k = *(const u8v*)&dp_##k[g*8]; \
                 u8v xV_##k = *(const u8v*)&xp_##k[g*8];
        SCAN_CH(LOADS)
#undef LOADS
#pragma unroll
        for (int j = 0; j < 8; ++j) {
            f4 Bv = *(const f4*)&bp[(size_t)(g*8 + j) * 32];
            f4 Cv = *(const f4*)&cp[(size_t)(g*8 + j) * 32];
            int t = t0 + g*8 + j;
            int ft = t + (t >> 5);
#define STEP2(k) { \
            float dj = us2f(dV_##k[j]); \
            float dx = dj * us2f(xV_##k[j]); \
            f2 jv = (f2){dj, dj}; \
            f2 e01 = jv*a01_##k, e23 = jv*a23_##k; \
            f2 x01 = (f2){exp2i(e01.x), exp2i(e01.y)}; \
            f2 x23 = (f2){exp2i(e23.x), exp2i(e23.y)}; \
            h01_##k = x01*h01_##k + (f2){dx*Bv[0], dx*Bv[1]}; \
            h23_##k = x23*h23_##k + (f2){dx*Bv[2], dx*Bv[3]}; \
            float s = (h01_##k.x*Cv[0] + h01_##k.y*Cv[1]) \
                    + (h23_##k.x*Cv[2] + h23_##k.y*Cv[3]); \
            s = sum4_quad(s); \
            if (ng == 0) ys[k][ft] = s; }
            SCAN_CH(STEP2)
#undef STEP2
        }
    }
    __syncthreads();

    // ------- gated output: pack 4 adjacent-d bf16, one 8B store per row ------
    {
        int i = tid * 8;                   // t range [i, i+8)
        int fi = i + (i >> 5);             // no 32-boundary crossing for k<8
#define GLOAD(k) u8v ug_##k = *(const u8v*)&g_t[cb0 + (size_t)(k)*ROWS + i];
        SCAN_CH(GLOAD)
#undef GLOAD
#pragma unroll
        for (int k = 0; k < 8; ++k) {
            u64 pk = 0;
#define GATE(q) { \
            float gv = us2f(ug_##q[k]); \
            float yv = ys[q][fi + k] * gv * rcpi(1.f + exp2i(-gv * L2E)); \
            pk |= (u64)f2us(yv) << (16*(q)); }
            SCAN_CH(GATE)
#undef GATE
            *(u64*)&ybf[(size_t)(rb + i + k) * D_ + d0] = pk;
        }
    }
}

extern "C" void kernel_launch(void* const* d_in, const int* in_sizes, int n_in,
                              void* d_out, int out_size, void* d_ws, size_t ws_size,
                              hipStream_t stream)
{
    const float* x      = (const float*)d_in[0];
    const float* rms_w  = (const float*)d_in[1];
    const float* in_W   = (const float*)d_in[2];
    const float* in_b   = (const float*)d_in[3];
    const float* conv_w = (const float*)d_in[4];
    const float* conv_b = (const float*)d_in[5];
    const float* A_log  = (const float*)d_in[6];
    const float* dbc_W  = (const float*)d_in[7];
    const float* dbc_b  = (const float*)d_in[8];
    const float* dup_W  = (const float*)d_in[9];
    const float* dup_b  = (const float*)d_in[10];
    const float* out_W  = (const float*)d_in[11];
    const float* out_b  = (const float*)d_in[12];
    float* out = (float*)d_out;

    // ---- workspace layout (~66 MB; 89.3 MB proven available) ----
    float* ws      = (float*)d_ws;
    us* projb = (us*)ws;                           // 16 MB bf16 [rows][2D] (x1|g), dead after conv
    us* g_t   = projb + (size_t)ROWS*2*D_;         // 8 MB bf16 [d][rows]
    float* bct     = (float*)(g_t + (size_t)ROWS*D_); // 256 KB fp32 [rows][32] (B|C)
    us* delta_t = (us*)(bct + (size_t)2*N_*ROWS);  // 8 MB bf16 [d][rows]
    us* hbf   = delta_t + (size_t)ROWS*D_;         // 4 MB
    us* x1cb  = hbf   + (size_t)ROWS*DM_;          // 8 MB [rows][D], dead after dbc-GEMM
    us* x1tb  = x1cb  + (size_t)ROWS*D_;           // 8 MB [d][rows]
    us* dtrb  = x1tb  + (size_t)ROWS*D_;           // 0.5 MB [rows][DTR]
    us* inWt  = dtrb  + (size_t)ROWS*DTR_;         // 8 MB  [4096][1024]
    us* dbcWt = inWt  + (size_t)2*D_*DM_;          // 0.64 MB [160][2048]
    us* dupWt = dbcWt + (size_t)NDBC*D_;           // 0.5 MB [2048][128]
    us* outWt = dupWt + (size_t)D_*DTR_;           // 4 MB  [1024][2048]
    float* dbcPart = (float*)projb;                // alias (projb dead after conv): 10.5 MB
    us* ybf   = x1cb;                              // alias (x1cb dead after dbc-GEMM), [rows][D]
    float* outPart = (float*)projb;                // alias: 32 MiB spans projb+g_t+bct+delta_t,
                                                   // all dead after scan; written in step 8
    dim3 tb(32, 8);
    // 1. weight prep + fused rmsnorm (6720 prep blocks + 2048 rms blocks)
    prep_weights<<<6720 + ROWS, tb, 0, stream>>>(in_W, out_W, dbc_W, dup_W,
                                                 inWt, outWt, dbcWt, dupWt,
                                                 x, rms_w, hbf);
    // 3. fused in_proj -> projb bf16 [rows][4096]  (BN=64, 1024 blocks)
    mgemm<4,false,64><<<dim3(64, 16), 256, 0, stream>>>(
        hbf, inWt, in_b, nullptr, projb, nullptr, nullptr, ROWS, 2*D_, DM_, DM_);
    // 4. conv + silu from projb -> x1cb + x1tb ; g -> g_t (64d x 32r tiles)
    conv_silu_kernel<<<dim3(D_/64, ROWS/32), 256, 0, stream>>>(
        projb, conv_w, conv_b, x1cb, x1tb, g_t);
    // 5. dbc partials, split-K x8: [2048 x 160], K=2048/8=256 per slice
    mgemm<5,false,128><<<dim3(2, 16, KSPL), 256, 0, stream>>>(
        x1cb, dbcWt, nullptr, dbcPart, nullptr, nullptr, nullptr,
        ROWS, NDBC, D_/KSPL, D_);
    // 5b. reduce partials + bias -> dtrb bf16 + bct fp32
    dbc_reduce<<<ROWS*NDBC/256, 256, 0, stream>>>(dbcPart, dbc_b, dtrb, bct);
    // 6. delta_t = softplus(dup_W^T @ dtr^T + dup_b) -> bf16 [2048 x 2048], K=128
    mgemm<1,true,32><<<dim3(64, 16), 256, 0, stream>>>(
        dupWt, dtrb, dup_b, nullptr, delta_t, nullptr, nullptr, D_, ROWS, DTR_, DTR_);
    // 7. quad-channel selective scan + gate -> ybf [rows][D] (XCD-local swz)
    scan_block_kernel<<<B_*D_/4, 128, 0, stream>>>(delta_t, x1tb, bct, A_log, g_t, ybf);
    // 8. out-proj partials, split-K x4 + BN=64: [2048 x 1024], 1024 blocks
    mgemm<5,false,64><<<dim3(16, 16, OSPL), 256, 0, stream>>>(
        ybf, outWt, nullptr, outPart, nullptr, nullptr, nullptr,
        ROWS, DM_, D_/OSPL, D_);
    // 8b. out = sum partials + out_b + residual
    out_reduce<<<ROWS*DM_/1024, 256, 0, stream>>>(outPart, out_b, x, out);
}

// Round 16
// 228.077 us; speedup vs baseline: 1.0166x; 1.0166x over previous
//
#include <hip/hip_runtime.h>
#include <math.h>

typedef unsigned short us;
typedef __attribute__((ext_vector_type(8))) short frag8;
typedef __attribute__((ext_vector_type(8))) unsigned short u8v;
typedef __attribute__((ext_vector_type(4))) float f4;
typedef __attribute__((ext_vector_type(2))) float f2;

#define B_   2
#define T_   1024
#define DM_  1024
#define D_   2048
#define N_   16
#define DTR_ 128
#define NDBC 160           // DTR + 2N
#define ROWS (B_*T_)       // 2048
#define EPS_ 1e-6f
#define NCH  32            // scan chunks per channel
#define CLEN (T_/NCH)      // 32 steps per chunk
#define KSPL 8             // split-K factor for dbc GEMM
#define OSPL 2             // split-K factor for out-proj GEMM (v16: was 4 --
                           // BN=32 keeps 1024 blocks; halves partial traffic)
#define L2E  1.44269504f   // log2(e)

__device__ __forceinline__ float us2f(us s){
    return __uint_as_float(((unsigned int)s) << 16);
}
__device__ __forceinline__ us f2us(float f){   // RTN-even fp32->bf16
    unsigned int u = __float_as_uint(f);
    return (us)((u + 0x7FFF + ((u >> 16) & 1)) >> 16);
}
// raw v_exp_f32: D = 2^S0 (1 instr; __expf emits v_mul(log2e)+v_exp)
__device__ __forceinline__ float exp2i(float x){
    float r; asm("v_exp_f32 %0, %1" : "=v"(r) : "v"(x)); return r;
}
__device__ __forceinline__ float rcpi(float x){
    return __builtin_amdgcn_rcpf(x);
}

// async global->LDS, 16B per lane. LDS dest is wave-uniform base + lane*16.
__device__ __forceinline__ void async16(const void* g, void* l){
    __builtin_amdgcn_global_load_lds(
        (const __attribute__((address_space(1))) void*)g,
        (__attribute__((address_space(3)))       void*)l, 16, 0, 0);
}

// one DPP accumulate step (dpp_ctrl must be a literal constant)
template<int CTRL>
__device__ __forceinline__ float dpp_add(float x){
    int t = __builtin_amdgcn_update_dpp(0, __float_as_int(x), CTRL, 0xF, 0xF, true);
    return x + __int_as_float(t);
}
// 4-lane (quad) sum via two quad_perm DPP adds; all 4 lanes get the total
__device__ __forceinline__ float sum4_quad(float x){
    x = dpp_add<0xB1>(x);   // quad_perm [1,0,3,2]
    x = dpp_add<0x4E>(x);   // quad_perm [2,3,0,1]
    return x;
}

// ---- combined preprocessing: 4 weight transposes + RMSNorm (merged) ----
__global__ __launch_bounds__(256) void prep_weights(
    const float* __restrict__ in_W,  const float* __restrict__ out_W,
    const float* __restrict__ dbc_W, const float* __restrict__ dup_W,
    us* __restrict__ inWt, us* __restrict__ outWt,
    us* __restrict__ dbcWt, us* __restrict__ dupWt,
    const float* __restrict__ x, const float* __restrict__ rms_w,
    us* __restrict__ hbf)
{
    int bid = blockIdx.x;
    int tx = threadIdx.x, ty = threadIdx.y;   // 32 x 8
    if (bid >= 6720) {   // ---- RMSNorm path ----
        const int row = bid - 6720;
        const int tid = ty * 32 + tx;
        const float* xr = x + (size_t)row * DM_;
        float vals[4], ss = 0.f;
#pragma unroll
        for (int i = 0; i < 4; ++i) { vals[i] = xr[tid + i*256]; ss += vals[i]*vals[i]; }
#pragma unroll
        for (int off = 32; off >= 1; off >>= 1) ss += __shfl_xor(ss, off, 64);
        __shared__ float red[4];
        if ((tid & 63) == 0) red[tid >> 6] = ss;
        __syncthreads();
        float scale = rsqrtf((red[0]+red[1]+red[2]+red[3]) / (float)DM_ + EPS_);
#pragma unroll
        for (int i = 0; i < 4; ++i)
            hbf[(size_t)row * DM_ + tid + i*256] = f2us(vals[i] * scale * rms_w[tid + i*256]);
        return;
    }
    __shared__ us tile[32][33];
    const float* src; us* dst; int C, R, TX, rel;
    if (bid < 4096)      { src = in_W;  dst = inWt;  R = 1024; C = 4096; TX = 128; rel = bid; }
    else if (bid < 6144) { src = out_W; dst = outWt; R = 2048; C = 1024; TX = 32;  rel = bid - 4096; }
    else if (bid < 6464) { src = dbc_W; dst = dbcWt; R = 2048; C = 160;  TX = 5;   rel = bid - 6144; }
    else                 { src = dup_W; dst = dupWt; R = 128;  C = 2048; TX = 64;  rel = bid - 6464; }
    int c0 = (rel % TX) * 32, r0 = (rel / TX) * 32;
    for (int i = ty; i < 32; i += 8)
        tile[i][tx] = f2us(src[(size_t)(r0 + i) * C + c0 + tx]);
    __syncthreads();
    for (int i = ty; i < 32; i += 8)
        dst[(size_t)(c0 + i) * R + r0 + tx] = tile[tx][i];
}

// ---------- MFMA GEMM: C[M,N] = A[M,K](bf16) * Bt[N,K](bf16)^T + bias --------
// Block tile 128 x BN (BN in {128,64,32}) / 4 waves / mfma_f32_16x16x32_bf16.
template<int EPI, bool RB, int BN>
__global__ __launch_bounds__(256) void mgemm(
    const us*    __restrict__ A,     // [M][ld]
    const us*    __restrict__ Bt,    // [N][ld]
    const float* __restrict__ bias,
    float*       __restrict__ Cf,
    us*          __restrict__ Caux,
    const float* __restrict__ resid, // EPI==2
    float*       __restrict__ bct,   // EPI==3
    int M, int N, int K, int ld)
{
    __shared__ us As[128*64];
    __shared__ us Bs[BN*64];
    const int tid = threadIdx.x;
    const int bm = blockIdx.y * 128;
    const int bn = blockIdx.x * BN;
    const int w = tid >> 6, lane = tid & 63;
    constexpr int WROWS = (BN == 128) ? 64 : 32;   // wave rows
    constexpr int NI = WROWS / 16;                 // 4 or 2
    constexpr int NJ = (BN == 32) ? 2 : 4;         // wave cols / 16
    const int wr = (BN == 128) ? (w >> 1) : w;
    const int wc = (BN == 128) ? (w & 1) : 0;
    const int m16 = lane & 15, quad = lane >> 4;

    const us* Ak = A;
    const us* Bk = Bt;
    if constexpr (EPI == 5) {
        const size_t koff = (size_t)blockIdx.z * K;
        Ak += koff; Bk += koff;
        Cf += (size_t)blockIdx.z * (size_t)M * N;
    }

    f4 acc[NI][NJ];
#pragma unroll
    for (int i = 0; i < NI; ++i)
#pragma unroll
        for (int j = 0; j < NJ; ++j)
            acc[i][j] = (f4){0.f, 0.f, 0.f, 0.f};

    for (int k0 = 0; k0 < K; k0 += 64) {
        __syncthreads();   // prior iter's frag reads done before overwrite
#pragma unroll
        for (int q = 0; q < 4; ++q) {          // A: 1024 chunks, 4/thread
            int cb = (w*4 + q)*64 + lane;
            int row = cb >> 3, c8 = (cb & 7)*8;
            async16(Ak + (size_t)(bm + row) * ld + k0 + c8, &As[cb*8]);
        }
#pragma unroll
        for (int q = 0; q < BN/32; ++q) {      // B: BN*8 chunks
            int cb = (w*(BN/32) + q)*64 + lane;
            int row = cb >> 3, c8 = (cb & 7)*8;
            async16(Bk + (size_t)(bn + row) * ld + k0 + c8, &Bs[cb*8]);
        }
        __syncthreads();   // vmcnt(0) drained here -> LDS valid
#pragma unroll
        for (int ks = 0; ks < 64; ks += 32) {
            frag8 af[NI], bfr[NJ];
#pragma unroll
            for (int i = 0; i < NI; ++i)
                af[i] = *(const frag8*)&As[(wr*WROWS + i*16 + m16)*64 + ks + quad*8];
#pragma unroll
            for (int j = 0; j < NJ; ++j)
                bfr[j] = *(const frag8*)&Bs[(wc*64 + j*16 + m16)*64 + ks + quad*8];
#pragma unroll
            for (int i = 0; i < NI; ++i)
#pragma unroll
                for (int j = 0; j < NJ; ++j)
                    acc[i][j] = __builtin_amdgcn_mfma_f32_16x16x32_bf16(af[i], bfr[j], acc[i][j], 0, 0, 0);
        }
    }

#pragma unroll
    for (int i = 0; i < NI; ++i) {
#pragma unroll
        for (int j = 0; j < NJ; ++j) {
            int col = bn + wc*64 + j*16 + m16;
            if (col >= N) continue;
            float bvc = (RB || EPI == 5) ? 0.f : bias[col];
#pragma unroll
            for (int r = 0; r < 4; ++r) {
                int row = bm + wr*WROWS + i*16 + quad*4 + r;
                float v = acc[i][j][r] + (EPI == 5 ? 0.f : (RB ? bias[row] : bvc));
                if constexpr (EPI == 1) {
                    // softplus -> bf16 (delta_t)
                    v = fmaxf(v, 0.f) + __logf(1.f + __expf(-fabsf(v)));
                    Caux[(size_t)row * N + col] = f2us(v);
                } else if constexpr (EPI == 2) {
                    v += resid[(size_t)row * N + col];
                    Cf[(size_t)row * N + col] = v;
                } else if constexpr (EPI == 3) {
                    if (col < DTR_) Caux[(size_t)row * DTR_ + col] = f2us(v);
                    else            bct [(size_t)row * 32 + (col - DTR_)] = v;
                } else if constexpr (EPI == 4) {
                    // all columns bf16 into projb [rows][N] (x1 | g)
                    Caux[(size_t)row * N + col] = f2us(v);
                } else {   // EPI 0 and EPI 5 (partial)
                    Cf[(size_t)row * N + col] = v;
                }
            }
        }
    }
}

// ---- split-K reduce for dbc: sum 8 partials + bias -> dtrb bf16 + bct fp32 ----
__global__ __launch_bounds__(256) void dbc_reduce(
    const float* __restrict__ part,   // [KSPL][ROWS][NDBC]
    const float* __restrict__ bias,
    us*    __restrict__ dtrb,         // [ROWS][DTR]
    float* __restrict__ bct)          // [ROWS][32]
{
    int idx = blockIdx.x * 256 + threadIdx.x;   // < ROWS*NDBC
    int row = idx / NDBC, col = idx - row * NDBC;
    float v = bias[col];
#pragma unroll
    for (int z = 0; z < KSPL; ++z)
        v += part[(size_t)z * ROWS * NDBC + idx];
    if (col < DTR_) dtrb[(size_t)row * DTR_ + col] = f2us(v);
    else            bct [(size_t)row * 32 + (col - DTR_)] = v;
}

// ---- split-K reduce for out-proj: sum OSPL partials + bias + residual ----
__global__ __launch_bounds__(256) void out_reduce(
    const float* __restrict__ part,   // [OSPL][ROWS][DM_]
    const float* __restrict__ bias,   // [DM_]
    const float* __restrict__ resid,  // [ROWS][DM_]
    float* __restrict__ out)
{
    int idx = (blockIdx.x * 256 + threadIdx.x) * 4;  // element index, f4 chunks
    int col = idx & (DM_ - 1);
    f4 v = *(const f4*)&bias[col];
    v += *(const f4*)&resid[idx];
#pragma unroll
    for (int z = 0; z < OSPL; ++z)
        v += *(const f4*)&part[(size_t)z * ROWS * DM_ + idx];
    *(f4*)&out[idx] = v;
}

// --- depthwise causal conv (K=4) + SiLU, 8 channels/thread (u8v taps) -------
__global__ __launch_bounds__(256) void conv_silu_kernel(
    const us*    __restrict__ projb,  // [rows][2D]: cols<D = x1pre, >=D = g
    const float* __restrict__ cw,
    const float* __restrict__ cb,
    us*          __restrict__ x1cb,
    us*          __restrict__ x1tb,
    us*          __restrict__ g_t)
{
    __shared__ us tileX[64][33];
    __shared__ us tileG[64][33];
    const int tid = threadIdx.x;
    const int dg = tid & 7, r = tid >> 3;   // 8 d-groups x 32 rows
    const int d0 = blockIdx.x * 64, r0 = blockIdx.y * 32;
    const int d8 = d0 + dg * 8;
    const int row = r0 + r;
    const int t = row & (T_ - 1);
    const us* base = projb + (size_t)row * (2*D_) + d8;
    const u8v zv = {0,0,0,0,0,0,0,0};
    u8v tap3 = *(const u8v*)base;
    u8v tap2 = (t >= 1) ? *(const u8v*)(base - 2*D_) : zv;
    u8v tap1 = (t >= 2) ? *(const u8v*)(base - 4*D_) : zv;
    u8v tap0 = (t >= 3) ? *(const u8v*)(base - 6*D_) : zv;
    u8v gv   = *(const u8v*)(base + D_);
    u8v outv;
#pragma unroll
    for (int e = 0; e < 8; ++e) {
        int d = d8 + e;
        f4 w = *(const f4*)&cw[d*4];
        float acc = cb[d];
        acc = fmaf(w[3], us2f(tap3[e]), acc);
        acc = fmaf(w[2], us2f(tap2[e]), acc);
        acc = fmaf(w[1], us2f(tap1[e]), acc);
        acc = fmaf(w[0], us2f(tap0[e]), acc);
        float sg = rcpi(1.f + exp2i(-acc * L2E));
        us uv = f2us(acc * sg);
        outv[e] = uv;
        tileX[dg*8 + e][r] = uv;
        tileG[dg*8 + e][r] = gv[e];
    }
    *(u8v*)&x1cb[(size_t)row * D_ + d8] = outv;
    __syncthreads();
#pragma unroll
    for (int it = 0; it < 8; ++it) {
        int dd = it*8 + (tid >> 5);     // 0..63
        int rr = tid & 31;
        x1tb[(size_t)(d0 + dd) * ROWS + r0 + rr] = tileX[dd][rr];
        g_t [(size_t)(d0 + dd) * ROWS + r0 + rr] = tileG[dd][rr];
    }
}

// ------- chunked selective scan + gate, TWO channels per block ---------------
// v16: reverted to v14's measured-best 2-channel form (4-channel regressed:
// LDS 35KB halved blocks/CU and the longer instruction burst reduced
// interleaving freedom). bf16 delta_t + x1tb (u8v); direct row-major ybf store
// with XCD-local swizzle; pass 2 recomputes a/d; exp2i; P via Dsum identity.
__global__ __launch_bounds__(128, 4) void scan_block_kernel(
    const us*    __restrict__ delta_t,  // [d][rows] bf16
    const us*    __restrict__ x1tb,
    const float* __restrict__ bct,    // [rows][32]: [0:16]=B_n, [16:32]=C_n
    const float* __restrict__ A_log,
    const us*    __restrict__ g_t,
    us*          __restrict__ ybf)    // [rows][D] row-major
{
    __shared__ float ysA[T_ + NCH];   // swizzle f(t) = t + (t>>5)
    __shared__ float ysB[T_ + NCH];
    __shared__ f4 PSl[2][NCH][9];     // [ch][c][2ng+(0,1)]; +1 pad col

    const int tid = threadIdx.x;       // 128
    // XCD-local channel mapping: XCD x gets swz in [x*256,(x+1)*256)
    const int lin = blockIdx.x;        // 0..2047
    const int swz = (lin & 7) * ((B_*D_/2) >> 3) + (lin >> 3);
    const int pr = swz & (D_/2 - 1);
    const int b  = swz >> 10;
    const int d0 = pr * 2;
    const int ng = tid & 3;            // states 4ng .. 4ng+3
    const int c  = tid >> 2;           // chunk 0..31
    const size_t rb  = (size_t)b * T_;
    const size_t cb0 = (size_t)d0 * ROWS + rb;   // ch0; ch1 at +ROWS
    const int t0 = c * CLEN;

    // per-state coefficients ac2_n = -exp(A_log[d][n]) * log2(e)
    f4 al0 = *(const f4*)&A_log[d0 * N_ + ng * 4];
    f4 al1 = *(const f4*)&A_log[(d0 + 1) * N_ + ng * 4];
    const f2 aA01 = (f2){-__expf(al0[0])*L2E, -__expf(al0[1])*L2E};
    const f2 aA23 = (f2){-__expf(al0[2])*L2E, -__expf(al0[3])*L2E};
    const f2 aB01 = (f2){-__expf(al1[0])*L2E, -__expf(al1[1])*L2E};
    const f2 aB23 = (f2){-__expf(al1[2])*L2E, -__expf(al1[3])*L2E};

    const us* __restrict__ dpA = delta_t + cb0 + t0;
    const us* __restrict__ dpB = dpA + ROWS;
    const us* __restrict__ xpA = x1tb + cb0 + t0;
    const us* __restrict__ xpB = xpA + ROWS;
    const float* __restrict__ bp = bct + (size_t)(rb + t0) * 32 + ng * 4;
    const float* __restrict__ cp = bp + 16;

    // ---------------- pass 1: per-chunk (Dsum, S), both channels -------------
    float DsA = 0.f, DsB = 0.f;
    f2 SA01={0.f,0.f}, SA23={0.f,0.f};
    f2 SB01={0.f,0.f}, SB23={0.f,0.f};
#pragma unroll
    for (int g = 0; g < 4; ++g) {
        u8v dA = *(const u8v*)&dpA[g*8];
        u8v dB = *(const u8v*)&dpB[g*8];
        u8v xA = *(const u8v*)&xpA[g*8];
        u8v xB = *(const u8v*)&xpB[g*8];
#pragma unroll
        for (int j = 0; j < 8; ++j) {
            float djA = us2f(dA[j]);
            float djB = us2f(dB[j]);
            f4 Bv = *(const f4*)&bp[(size_t)(g*8 + j) * 32];
            float dxA = djA * us2f(xA[j]);
            float dxB = djB * us2f(xB[j]);
            DsA += djA; DsB += djB;
            f2 jA = (f2){djA, djA}, jB = (f2){djB, djB};
            f2 eA01 = jA*aA01, eA23 = jA*aA23;
            f2 eB01 = jB*aB01, eB23 = jB*aB23;
            f2 xA01 = (f2){exp2i(eA01.x), exp2i(eA01.y)};
            f2 xA23 = (f2){exp2i(eA23.x), exp2i(eA23.y)};
            f2 xB01 = (f2){exp2i(eB01.x), exp2i(eB01.y)};
            f2 xB23 = (f2){exp2i(eB23.x), exp2i(eB23.y)};
            SA01 = xA01*SA01 + (f2){dxA*Bv[0], dxA*Bv[1]};
            SA23 = xA23*SA23 + (f2){dxA*Bv[2], dxA*Bv[3]};
            SB01 = xB01*SB01 + (f2){dxB*Bv[0], dxB*Bv[1]};
            SB23 = xB23*SB23 + (f2){dxB*Bv[2], dxB*Bv[3]};
        }
    }
    // P_n = exp2(ac2_n * Dsum) -- replaces per-step P products
    f2 PA01 = (f2){exp2i(aA01.x*DsA), exp2i(aA01.y*DsA)};
    f2 PA23 = (f2){exp2i(aA23.x*DsA), exp2i(aA23.y*DsA)};
    f2 PB01 = (f2){exp2i(aB01.x*DsB), exp2i(aB01.y*DsB)};
    f2 PB23 = (f2){exp2i(aB23.x*DsB), exp2i(aB23.y*DsB)};
    PSl[0][c][2*ng+0] = (f4){PA01.x,PA01.y,SA01.x,SA01.y};
    PSl[0][c][2*ng+1] = (f4){PA23.x,PA23.y,SA23.x,SA23.y};
    PSl[1][c][2*ng+0] = (f4){PB01.x,PB01.y,SB01.x,SB01.y};
    PSl[1][c][2*ng+1] = (f4){PB23.x,PB23.y,SB23.x,SB23.y};
    __syncthreads();

    // ---------------- inter-chunk prefix (serial over c2 < c) ----------------
    f2 hA01={0.f,0.f}, hA23={0.f,0.f}, hB01={0.f,0.f}, hB23={0.f,0.f};
    for (int c2 = 0; c2 < c; ++c2) {
        f4 p0 = PSl[0][c2][2*ng+0], p1 = PSl[0][c2][2*ng+1];
        f4 q0 = PSl[1][c2][2*ng+0], q1 = PSl[1][c2][2*ng+1];
        hA01 = (f2){p0[0],p0[1]}*hA01 + (f2){p0[2],p0[3]};
        hA23 = (f2){p1[0],p1[1]}*hA23 + (f2){p1[2],p1[3]};
        hB01 = (f2){q0[0],q0[1]}*hB01 + (f2){q0[2],q0[3]};
        hB23 = (f2){q1[0],q1[1]}*hB23 + (f2){q1[2],q1[3]};
    }

    // ---------------- pass 2: recompute a/d, emit y (both channels) ----------
#pragma unroll
    for (int g = 0; g < 4; ++g) {
        u8v dA = *(const u8v*)&dpA[g*8];
        u8v dB = *(const u8v*)&dpB[g*8];
        u8v xA = *(const u8v*)&xpA[g*8];
        u8v xB = *(const u8v*)&xpB[g*8];
#pragma unroll
        for (int j = 0; j < 8; ++j) {
            float djA = us2f(dA[j]);
            float djB = us2f(dB[j]);
            f4 Bv = *(const f4*)&bp[(size_t)(g*8 + j) * 32];
            f4 Cv = *(const f4*)&cp[(size_t)(g*8 + j) * 32];
            float dxA = djA * us2f(xA[j]);
            float dxB = djB * us2f(xB[j]);
            f2 jA = (f2){djA, djA}, jB = (f2){djB, djB};
            f2 eA01 = jA*aA01, eA23 = jA*aA23;
            f2 eB01 = jB*aB01, eB23 = jB*aB23;
            f2 xA01 = (f2){exp2i(eA01.x), exp2i(eA01.y)};
            f2 xA23 = (f2){exp2i(eA23.x), exp2i(eA23.y)};
            f2 xB01 = (f2){exp2i(eB01.x), exp2i(eB01.y)};
            f2 xB23 = (f2){exp2i(eB23.x), exp2i(eB23.y)};
            hA01 = xA01*hA01 + (f2){dxA*Bv[0], dxA*Bv[1]};
            hA23 = xA23*hA23 + (f2){dxA*Bv[2], dxA*Bv[3]};
            hB01 = xB01*hB01 + (f2){dxB*Bv[0], dxB*Bv[1]};
            hB23 = xB23*hB23 + (f2){dxB*Bv[2], dxB*Bv[3]};
            float sA = (hA01.x*Cv[0] + hA01.y*Cv[1]) + (hA23.x*Cv[2] + hA23.y*Cv[3]);
            float sB = (hB01.x*Cv[0] + hB01.y*Cv[1]) + (hB23.x*Cv[2] + hB23.y*Cv[3]);
            sA = sum4_quad(sA);
            sB = sum4_quad(sB);
            int t = t0 + g*8 + j;
            if (ng == 0) { ysA[t + (t >> 5)] = sA; ysB[t + (t >> 5)] = sB; }
        }
    }
    __syncthreads();

    // ------- gated output: pack (d0,d0+1) bf16 pair, store row-major -------
    {
        int i = tid * 8;                   // t range [i, i+8)
        int fi = i + (i >> 5);             // no 32-boundary crossing for k<8
        u8v ugA = *(const u8v*)&g_t[cb0 + i];
        u8v ugB = *(const u8v*)&g_t[cb0 + ROWS + i];
#pragma unroll
        for (int k = 0; k < 8; ++k) {
            float gA = us2f(ugA[k]), gB = us2f(ugB[k]);
            float yA = ysA[fi + k] * gA * rcpi(1.f + exp2i(-gA * L2E));
            float yB = ysB[fi + k] * gB * rcpi(1.f + exp2i(-gB * L2E));
            unsigned int pk = (unsigned int)f2us(yA) | ((unsigned int)f2us(yB) << 16);
            *(unsigned int*)&ybf[(size_t)(rb + i + k) * D_ + d0] = pk;
        }
    }
}

extern "C" void kernel_launch(void* const* d_in, const int* in_sizes, int n_in,
                              void* d_out, int out_size, void* d_ws, size_t ws_size,
                              hipStream_t stream)
{
    const float* x      = (const float*)d_in[0];
    const float* rms_w  = (const float*)d_in[1];
    const float* in_W   = (const float*)d_in[2];
    const float* in_b   = (const float*)d_in[3];
    const float* conv_w = (const float*)d_in[4];
    const float* conv_b = (const float*)d_in[5];
    const float* A_log  = (const float*)d_in[6];
    const float* dbc_W  = (const float*)d_in[7];
    const float* dbc_b  = (const float*)d_in[8];
    const float* dup_W  = (const float*)d_in[9];
    const float* dup_b  = (const float*)d_in[10];
    const float* out_W  = (const float*)d_in[11];
    const float* out_b  = (const float*)d_in[12];
    float* out = (float*)d_out;

    // ---- workspace layout (~66 MB; 89.3 MB proven available) ----
    float* ws      = (float*)d_ws;
    us* projb = (us*)ws;                           // 16 MB bf16 [rows][2D] (x1|g), dead after conv
    us* g_t   = projb + (size_t)ROWS*2*D_;         // 8 MB bf16 [d][rows]
    float* bct     = (float*)(g_t + (size_t)ROWS*D_); // 256 KB fp32 [rows][32] (B|C)
    us* delta_t = (us*)(bct + (size_t)2*N_*ROWS);  // 8 MB bf16 [d][rows]
    us* hbf   = delta_t + (size_t)ROWS*D_;         // 4 MB
    us* x1cb  = hbf   + (size_t)ROWS*DM_;          // 8 MB [rows][D], dead after dbc-GEMM
    us* x1tb  = x1cb  + (size_t)ROWS*D_;           // 8 MB [d][rows]
    us* dtrb  = x1tb  + (size_t)ROWS*D_;           // 0.5 MB [rows][DTR]
    us* inWt  = dtrb  + (size_t)ROWS*DTR_;         // 8 MB  [4096][1024]
    us* dbcWt = inWt  + (size_t)2*D_*DM_;          // 0.64 MB [160][2048]
    us* dupWt = dbcWt + (size_t)NDBC*D_;           // 0.5 MB [2048][128]
    us* outWt = dupWt + (size_t)D_*DTR_;           // 4 MB  [1024][2048]
    float* dbcPart = (float*)projb;                // alias (projb dead after conv): 10.5 MB
    us* ybf   = x1cb;                              // alias (x1cb dead after dbc-GEMM), [rows][D]
    float* outPart = (float*)projb;                // alias: 16 MiB [2][2048][1024] fits projb,
                                                   // dead after scan; written in step 8
    dim3 tb(32, 8);
    // 1. weight prep + fused rmsnorm (6720 prep blocks + 2048 rms blocks)
    prep_weights<<<6720 + ROWS, tb, 0, stream>>>(in_W, out_W, dbc_W, dup_W,
                                                 inWt, outWt, dbcWt, dupWt,
                                                 x, rms_w, hbf);
    // 3. fused in_proj -> projb bf16 [rows][4096]  (BN=64, 1024 blocks)
    mgemm<4,false,64><<<dim3(64, 16), 256, 0, stream>>>(
        hbf, inWt, in_b, nullptr, projb, nullptr, nullptr, ROWS, 2*D_, DM_, DM_);
    // 4. conv + silu from projb -> x1cb + x1tb ; g -> g_t (64d x 32r tiles)
    conv_silu_kernel<<<dim3(D_/64, ROWS/32), 256, 0, stream>>>(
        projb, conv_w, conv_b, x1cb, x1tb, g_t);
    // 5. dbc partials, split-K x8: [2048 x 160], K=2048/8=256 per slice
    mgemm<5,false,128><<<dim3(2, 16, KSPL), 256, 0, stream>>>(
        x1cb, dbcWt, nullptr, dbcPart, nullptr, nullptr, nullptr,
        ROWS, NDBC, D_/KSPL, D_);
    // 5b. reduce partials + bias -> dtrb bf16 + bct fp32
    dbc_reduce<<<ROWS*NDBC/256, 256, 0, stream>>>(dbcPart, dbc_b, dtrb, bct);
    // 6. delta_t = softplus(dup_W^T @ dtr^T + dup_b) -> bf16 [2048 x 2048], K=128
    mgemm<1,true,32><<<dim3(64, 16), 256, 0, stream>>>(
        dupWt, dtrb, dup_b, nullptr, delta_t, nullptr, nullptr, D_, ROWS, DTR_, DTR_);
    // 7. paired-channel selective scan + gate -> ybf [rows][D] (XCD-local swz)
    scan_block_kernel<<<B_*D_/2, 128, 0, stream>>>(delta_t, x1tb, bct, A_log, g_t, ybf);
    // 8. out-proj partials, split-K x2 + BN=32: [2048 x 1024], 1024 blocks
    //    (v16: OSPL 4->2 with BN=32 keeps 4 blocks/CU while halving the 32MiB
    //     fp32 partial round-trip)
    mgemm<5,false,32><<<dim3(32, 16, OSPL), 256, 0, stream>>>(
        ybf, outWt, nullptr, outPart, nullptr, nullptr, nullptr,
        ROWS, DM_, D_/OSPL, D_);
    // 8b. out = sum partials + out_b + residual
    out_reduce<<<ROWS*DM_/1024, 256, 0, stream>>>(outPart, out_b, x, out);
}